// Round 1
// baseline (918.764 us; speedup 1.0000x reference)
//
#include <hip/hip_runtime.h>
#include <hip/hip_bf16.h>

// Shapes (fixed): B=128, F=8, K=256, D=256, H=256, HFF=512, L=2, M_PREV=2
#define B_   128
#define F_   8
#define K_   256
#define D_   256
#define H_   256
#define HFF_ 512
#define RT   64   // candidates per block

typedef _Float16 half8  __attribute__((ext_vector_type(8)));  // f16x8 MFMA frag
typedef _Float16 half4v __attribute__((ext_vector_type(4)));
typedef float floatx4   __attribute__((ext_vector_type(4)));  // MFMA acc

#define MFMAH(a,b,c) __builtin_amdgcn_mfma_f32_16x16x32_f16(a,b,c,0,0,0)

// LDS strides (halves): 260 -> 130 dwords == 2 mod 32 (conflict-free b128);
// 132 -> 66 dwords == 2 mod 32.
// R10 LDS: hA 33280 + hmA dbuf 33792 + x/xh 2048 + dist 2048 = 71168 B
//          -> 2 blocks/CU x 8 waves = 16 waves/CU (was 3x4=12).
#define HA_S  260
#define HMA_S 132

// ---------------------------------------------------------------------------
// R9: fused prep — one launch for (h0->u), v, and the fp16 weight shuffle.
// blocks [0,256): u[k] = (cb[k]@Win + bin)@Wcat_top   (h0 never hits HBM)
// blocks [256,1280): v[bf] = bcat + xhat[bf]@Wcat_bot
// blocks [1280,3584): weight fragment shuffle (W1/W2/Wout -> fp16 frag order)
__global__ void k_prep(const float* __restrict__ cb, const float* __restrict__ Win,
                       const float* __restrict__ bin, const float* __restrict__ Wcat,
                       const float* __restrict__ bcat, const float* __restrict__ xhat,
                       const float* __restrict__ W1, const float* __restrict__ W2,
                       const float* __restrict__ Wout,
                       float* __restrict__ u, float* __restrict__ v,
                       _Float16* __restrict__ w1f, _Float16* __restrict__ w2f,
                       _Float16* __restrict__ wof) {
  const int blk = blockIdx.x, t = threadIdx.x;
  if (blk < K_) {
    __shared__ float row[D_];
    __shared__ float h0row[H_];
    row[t] = cb[blk * D_ + t];
    __syncthreads();
    float acc = bin[t];
    #pragma unroll 4
    for (int i = 0; i < D_; ++i) acc = fmaf(row[i], Win[i * H_ + t], acc);
    h0row[t] = acc;
    __syncthreads();
    float acc2 = 0.f;
    #pragma unroll 4
    for (int i = 0; i < H_; ++i) acc2 = fmaf(h0row[i], Wcat[i * H_ + t], acc2);
    u[blk * H_ + t] = acc2;
  } else if (blk < K_ + B_ * F_) {
    __shared__ float row2[D_];
    const int bf = blk - K_;
    row2[t] = xhat[bf * D_ + t];
    __syncthreads();
    float acc = bcat[t];
    #pragma unroll 4
    for (int i = 0; i < D_; ++i) acc = fmaf(row2[i], Wcat[(H_ + i) * H_ + t], acc);
    v[bf * H_ + t] = acc;
  } else {
    const int e = (blk - (K_ + B_ * F_)) * 256 + t;
    const float* src; _Float16* dst; int N, NT, le;
    if (e < 262144) {
      const int layer = e >> 17; le = e & 131071;
      src = W1 + layer * (H_ * HFF_); dst = w1f + layer * (H_ * HFF_);
      N = HFF_; NT = 32;
    } else if (e < 524288) {
      const int e2 = e - 262144;
      const int layer = e2 >> 17; le = e2 & 131071;
      src = W2 + layer * (HFF_ * H_); dst = w2f + layer * (HFF_ * H_);
      N = H_; NT = 16;
    } else {
      le = e - 524288; src = Wout; dst = wof; N = D_; NT = 16;
    }
    const int jj = le & 7, lane = (le >> 3) & 63, r = le >> 9;
    const int ntile = r % NT, kstep = r / NT;
    const int row = kstep * 32 + (lane >> 4) * 8 + jj;
    const int colc = ntile * 16 + (lane & 15);
    dst[le] = (_Float16)src[row * N + colc];
  }
}

// ---------------------------------------------------------------------------
// R10 MFMA main kernel: 512 threads (8 waves), hmA double-buffered, pipelined
// chunk loop: phase = {GEMM1(ch+1) || GEMM2(ch)} with ONE barrier per chunk.
__global__ __launch_bounds__(512, 4) void k_main(
    const float* __restrict__ u, const float* __restrict__ v,
    const _Float16* __restrict__ w1f, const float* __restrict__ b1,
    const _Float16* __restrict__ w2f, const float* __restrict__ b2,
    const _Float16* __restrict__ woutf, const float* __restrict__ bout,
    const float* __restrict__ cb, const float* __restrict__ xhat,
    const float* __restrict__ x, float* __restrict__ dists) {
  __shared__ _Float16 hA[64][HA_S];       // 33280 B
  __shared__ _Float16 hmA[2][64][HMA_S];  // 33792 B (double buffer)
  __shared__ float x_s[D_], xh_s[D_];     // 2048 B
  __shared__ float dist_s[8][64];         // 2048 B

  const int t = threadIdx.x;              // 0..511
  const int blk = blockIdx.x;
  const int bf = blk >> 2, k0 = (blk & 3) << 6;
  const int b = bf >> 3, f = bf & 7;
  const int wave = t >> 6, lane = t & 63; // wave 0..7
  const int col = lane & 15, quad = lane >> 4;
  const int lane8 = lane * 8;

  if (t < D_) {
    x_s[t]  = x[b * D_ + t];
    xh_s[t] = xhat[bf * D_ + t];
  }

  // stage h = u + v -> fp16, packed 16B writes (512 threads: 32 cols each)
  {
    const int r = t >> 3, c0 = (t & 7) * 32;
    const float* up = u + (k0 + r) * H_ + c0;
    const float* vp = v + bf * H_ + c0;
    #pragma unroll
    for (int j = 0; j < 32; j += 8) {
      float4 uA = *(const float4*)(up + j);
      float4 vA = *(const float4*)(vp + j);
      float4 uB = *(const float4*)(up + j + 4);
      float4 vB = *(const float4*)(vp + j + 4);
      half8 hv8;
      hv8[0] = (_Float16)(uA.x + vA.x); hv8[1] = (_Float16)(uA.y + vA.y);
      hv8[2] = (_Float16)(uA.z + vA.z); hv8[3] = (_Float16)(uA.w + vA.w);
      hv8[4] = (_Float16)(uB.x + vB.x); hv8[5] = (_Float16)(uB.y + vB.y);
      hv8[6] = (_Float16)(uB.z + vB.z); hv8[7] = (_Float16)(uB.w + vB.w);
      *(half8*)&hA[r][c0 + j] = hv8;
    }
  }
  __syncthreads();

  const floatx4 zero4 = {0.f, 0.f, 0.f, 0.f};

  floatx4 acc2[2][4];   // [out-feature tile][candidate-row tile], per wave

  // GEMM1': hm' = relu(W1[:,chunk]^T @ h^T + b1) -> hm (one 16-feat tile/wave)
  auto gemm1 = [&](const _Float16* __restrict__ w1_l,
                   const float* __restrict__ b1l, const int ch,
                   _Float16 (* __restrict__ hm)[HMA_S]) {
    floatx4 acc1[4] = {zero4, zero4, zero4, zero4};
    const _Float16* w1_b = w1_l + (ch * 8 + wave) * 512 + lane8;
    #pragma unroll 4
    for (int ks = 0; ks < 8; ++ks) {
      half8 b0  = *(const half8*)&hA[col][ks * 32 + quad * 8];
      half8 b1v = *(const half8*)&hA[16 + col][ks * 32 + quad * 8];
      half8 b2v = *(const half8*)&hA[32 + col][ks * 32 + quad * 8];
      half8 b3v = *(const half8*)&hA[48 + col][ks * 32 + quad * 8];
      half8 aw  = *(const half8*)(w1_b + ks * 32 * 512);
      acc1[0] = MFMAH(aw, b0,  acc1[0]);
      acc1[1] = MFMAH(aw, b1v, acc1[1]);
      acc1[2] = MFMAH(aw, b2v, acc1[2]);
      acc1[3] = MFMAH(aw, b3v, acc1[3]);
    }
    // bias + relu -> fp16, packed 8B stores
    const int floc = wave * 16 + quad * 4;
    float4 bb = *(const float4*)&b1l[ch * 128 + floc];
    #pragma unroll
    for (int nt = 0; nt < 4; ++nt) {
      const int row = nt * 16 + col;
      half4v nh;
      #pragma unroll
      for (int p = 0; p < 4; ++p)
        nh[p] = (_Float16)fmaxf(acc1[nt][p] + ((const float*)&bb)[p], 0.f);
      *(half4v*)&hm[row][floc] = nh;
    }
  };

  // GEMM2': acc2 += W2[chunk,:]^T @ hm'^T  (two 16-feat tiles/wave)
  auto gemm2 = [&](const _Float16* __restrict__ w2_l, const int ch,
                   const _Float16 (* __restrict__ hm)[HMA_S]) {
    const _Float16* w2_b = w2_l + (ch * 64 + wave * 2) * 512 + lane8;
    #pragma unroll 2
    for (int ks = 0; ks < 4; ++ks) {
      half8 b0  = *(const half8*)&hm[col][ks * 32 + quad * 8];
      half8 b1v = *(const half8*)&hm[16 + col][ks * 32 + quad * 8];
      half8 b2v = *(const half8*)&hm[32 + col][ks * 32 + quad * 8];
      half8 b3v = *(const half8*)&hm[48 + col][ks * 32 + quad * 8];
      const int ko = ks * 16 * 512;
      #pragma unroll
      for (int mt = 0; mt < 2; ++mt) {
        half8 aw = *(const half8*)(w2_b + ko + mt * 512);
        acc2[mt][0] = MFMAH(aw, b0,  acc2[mt][0]);
        acc2[mt][1] = MFMAH(aw, b1v, acc2[mt][1]);
        acc2[mt][2] = MFMAH(aw, b2v, acc2[mt][2]);
        acc2[mt][3] = MFMAH(aw, b3v, acc2[mt][3]);
      }
    }
  };

  #pragma unroll 1
  for (int l = 0; l < 2; ++l) {
    const _Float16* w1_l = w1f + l * (H_ * HFF_);
    const _Float16* w2_l = w2f + l * (HFF_ * H_);
    const float* b1l = b1 + l * HFF_;
    const float* b2l = b2 + l * H_;

    #pragma unroll
    for (int mt = 0; mt < 2; ++mt)
      #pragma unroll
      for (int nt = 0; nt < 4; ++nt) acc2[mt][nt] = zero4;

    // prologue: fill hmA[0]
    gemm1(w1_l, b1l, 0, hmA[0]);
    __syncthreads();

    // pipelined phases: GEMM1(ch+1) -> hmA[(ch+1)&1] || GEMM2(ch) <- hmA[ch&1]
    #pragma unroll 1
    for (int ch = 0; ch < 3; ++ch) {
      gemm1(w1_l, b1l, ch + 1, hmA[(ch + 1) & 1]);
      gemm2(w2_l, ch, hmA[ch & 1]);
      __syncthreads();
    }
    gemm2(w2_l, 3, hmA[1]);   // drain: no barrier needed (hA untouched by gemm2)

    // ---- residual: h += acc2 + b2, packed 8B read/modify/write ----
    #pragma unroll
    for (int mt = 0; mt < 2; ++mt) {
      const int feat0 = (wave * 2 + mt) * 16 + quad * 4;
      float4 bb = *(const float4*)&b2l[feat0];
      #pragma unroll
      for (int nt = 0; nt < 4; ++nt) {
        const int row = nt * 16 + col;
        half4v oh = *(half4v*)&hA[row][feat0];
        half4v nh;
        #pragma unroll
        for (int p = 0; p < 4; ++p)
          nh[p] = (_Float16)((float)oh[p] + acc2[mt][nt][p] + ((const float*)&bb)[p]);
        *(half4v*)&hA[row][feat0] = nh;
      }
    }
    __syncthreads();
  }

  // ---- GEMM3': cw' = Wout^T @ h^T (+bout+cb+xhat), then distance ----
  floatx4 acc3[2][4];
  #pragma unroll
  for (int mt = 0; mt < 2; ++mt)
    #pragma unroll
    for (int nt = 0; nt < 4; ++nt) acc3[mt][nt] = zero4;

  const _Float16* wo_b = woutf + (wave * 2) * 512 + lane8;
  #pragma unroll 2
  for (int ks = 0; ks < 8; ++ks) {
    half8 b0  = *(const half8*)&hA[col][ks * 32 + quad * 8];
    half8 b1v = *(const half8*)&hA[16 + col][ks * 32 + quad * 8];
    half8 b2v = *(const half8*)&hA[32 + col][ks * 32 + quad * 8];
    half8 b3v = *(const half8*)&hA[48 + col][ks * 32 + quad * 8];
    const int ko = ks * 16 * 512;
    #pragma unroll
    for (int mt = 0; mt < 2; ++mt) {
      half8 aw = *(const half8*)(wo_b + ko + mt * 512);
      acc3[mt][0] = MFMAH(aw, b0,  acc3[mt][0]);
      acc3[mt][1] = MFMAH(aw, b1v, acc3[mt][1]);
      acc3[mt][2] = MFMAH(aw, b2v, acc3[mt][2]);
      acc3[mt][3] = MFMAH(aw, b3v, acc3[mt][3]);
    }
  }

  float s[4] = {0.f, 0.f, 0.f, 0.f};
  #pragma unroll
  for (int mt = 0; mt < 2; ++mt) {
    const int d0 = (wave * 2 + mt) * 16 + quad * 4;
    float4 bo  = *(const float4*)&bout[d0];
    float4 xv  = *(const float4*)&x_s[d0];
    float4 xh4 = *(const float4*)&xh_s[d0];
    #pragma unroll
    for (int nt = 0; nt < 4; ++nt) {
      float4 cbv = *(const float4*)&cb[(k0 + nt * 16 + col) * D_ + d0];
      #pragma unroll
      for (int p = 0; p < 4; ++p) {
        float base = ((const float*)&bo)[p] + ((const float*)&xh4)[p];
        float xx = ((const float*)&xv)[p];
        float cw = acc3[mt][nt][p] + base + ((const float*)&cbv)[p];
        s[nt] += cw * (cw - 2.f * xx);   // -||x||^2 const: argmin-invariant
      }
    }
  }
  #pragma unroll
  for (int nt = 0; nt < 4; ++nt) {
    s[nt] += __shfl_xor(s[nt], 16, 64);
    s[nt] += __shfl_xor(s[nt], 32, 64);
  }
  if (quad == 0) {
    #pragma unroll
    for (int nt = 0; nt < 4; ++nt)
      dist_s[wave][nt * 16 + col] = s[nt];
  }
  __syncthreads();
  if (t < 64) {
    float d = 0.f;
    #pragma unroll
    for (int w = 0; w < 8; ++w) d += dist_s[w][t];
    dists[b * (F_ * K_) + f * K_ + k0 + t] = d;
  }
}

// ---------------------------------------------------------------------------
// Top-8 candidates per b from approx dists (iterative selection).
__global__ void k_top8(const float* __restrict__ dists, int* __restrict__ topi) {
  __shared__ float ds[F_ * K_];
  __shared__ float bv[256];
  __shared__ int bi_s[256];
  const int b = blockIdx.x, t = threadIdx.x;
  for (int j = t; j < F_ * K_; j += 256) ds[j] = dists[b * (F_ * K_) + j];
  __syncthreads();
  for (int pass = 0; pass < 8; ++pass) {
    float best = 3.4e38f; int bi = 0;
    for (int j = t; j < F_ * K_; j += 256) {
      const float dv = ds[j];
      if (dv < best) { best = dv; bi = j; }
    }
    bv[t] = best; bi_s[t] = bi;
    __syncthreads();
    for (int s = 128; s > 0; s >>= 1) {
      if (t < s) {
        const float ov = bv[t + s]; const int oi = bi_s[t + s];
        if (ov < bv[t] || (ov == bv[t] && oi < bi_s[t])) { bv[t] = ov; bi_s[t] = oi; }
      }
      __syncthreads();
    }
    if (t == 0) { topi[b * 8 + pass] = bi_s[0]; ds[bi_s[0]] = 3.4e38f; }
    __syncthreads();
  }
}

// ---------------------------------------------------------------------------
// Exact fp32 rescore of one candidate row per block (same math as R2 pass).
__global__ void k_rescore(const float* __restrict__ u, const float* __restrict__ v,
                          const float* __restrict__ W1, const float* __restrict__ b1,
                          const float* __restrict__ W2, const float* __restrict__ b2,
                          const float* __restrict__ Wout, const float* __restrict__ bout,
                          const float* __restrict__ cb, const float* __restrict__ xhat,
                          const float* __restrict__ x, const int* __restrict__ topi,
                          float* __restrict__ resc) {
  __shared__ float hs[H_];
  __shared__ float hms[HFF_];
  __shared__ float red[256];
  const int bc = blockIdx.x, t = threadIdx.x;
  const int b = bc >> 3;
  const int idx = topi[bc];
  const int f = idx >> 8, k = idx & 255;
  const int bf = b * F_ + f;

  hs[t] = u[k * H_ + t] + v[bf * H_ + t];
  __syncthreads();
  for (int l = 0; l < 2; ++l) {
    const float* W1l = W1 + l * (H_ * HFF_);
    const float* W2l = W2 + l * (HFF_ * H_);
    float a0 = b1[l * HFF_ + t], a1 = b1[l * HFF_ + 256 + t];
    for (int i = 0; i < H_; ++i) {
      const float hv = hs[i];
      a0 = fmaf(hv, W1l[i * HFF_ + t], a0);
      a1 = fmaf(hv, W1l[i * HFF_ + 256 + t], a1);
    }
    hms[t] = fmaxf(a0, 0.f);
    hms[t + 256] = fmaxf(a1, 0.f);
    __syncthreads();
    float hn = hs[t] + b2[l * H_ + t];
    for (int jj = 0; jj < HFF_; ++jj)
      hn = fmaf(hms[jj], W2l[jj * H_ + t], hn);
    __syncthreads();
    hs[t] = hn;
    __syncthreads();
  }
  float cw = bout[t] + cb[k * D_ + t] + xhat[bf * D_ + t];
  for (int i = 0; i < H_; ++i) cw = fmaf(hs[i], Wout[i * D_ + t], cw);
  red[t] = cw * (cw - 2.f * x[b * D_ + t]);
  __syncthreads();
  for (int s = 128; s > 0; s >>= 1) {
    if (t < s) red[t] += red[t + s];
    __syncthreads();
  }
  if (t == 0) resc[bc] = red[0];
}

// ---------------------------------------------------------------------------
// Pick exact argmin among 8 rescored candidates; recompute winner; write out.
__global__ void k_final(const float* __restrict__ u, const float* __restrict__ v,
                        const float* __restrict__ W1, const float* __restrict__ b1,
                        const float* __restrict__ W2, const float* __restrict__ b2,
                        const float* __restrict__ Wout, const float* __restrict__ bout,
                        const float* __restrict__ cb, const float* __restrict__ xhat,
                        const int* __restrict__ codes, const int* __restrict__ topi,
                        const float* __restrict__ resc, float* __restrict__ out) {
  __shared__ float hs[H_];
  __shared__ float hms[HFF_];
  __shared__ int idx_sh;
  const int b = blockIdx.x, t = threadIdx.x;
  if (t == 0) {
    float bd = 3.4e38f; int bidx = 1 << 30;
    for (int c = 0; c < 8; ++c) {
      const float d = resc[b * 8 + c];
      const int ix = topi[b * 8 + c];
      if (d < bd || (d == bd && ix < bidx)) { bd = d; bidx = ix; }
    }
    idx_sh = bidx;
  }
  __syncthreads();
  const int idx = idx_sh;
  const int f = idx >> 8, k = idx & 255;
  const int bf = b * F_ + f;

  hs[t] = u[k * H_ + t] + v[bf * H_ + t];
  __syncthreads();
  for (int l = 0; l < 2; ++l) {
    const float* W1l = W1 + l * (H_ * HFF_);
    const float* W2l = W2 + l * (HFF_ * H_);
    float a0 = b1[l * HFF_ + t], a1 = b1[l * HFF_ + 256 + t];
    for (int i = 0; i < H_; ++i) {
      const float hv = hs[i];
      a0 = fmaf(hv, W1l[i * HFF_ + t], a0);
      a1 = fmaf(hv, W1l[i * HFF_ + 256 + t], a1);
    }
    hms[t] = fmaxf(a0, 0.f);
    hms[t + 256] = fmaxf(a1, 0.f);
    __syncthreads();
    float hn = hs[t] + b2[l * H_ + t];
    for (int jj = 0; jj < HFF_; ++jj)
      hn = fmaf(hms[jj], W2l[jj * H_ + t], hn);
    __syncthreads();
    hs[t] = hn;
    __syncthreads();
  }
  float cw = bout[t] + cb[k * D_ + t] + xhat[bf * D_ + t];
  for (int i = 0; i < H_; ++i) cw = fmaf(hs[i], Wout[i * D_ + t], cw);

  out[b * D_ + t] = cw;
  if (t < 2)
    out[B_ * D_ + t * B_ + b] = (float)codes[t * B_ + b];
  else if (t == 2)
    out[B_ * D_ + 2 * B_ + b] = (float)idx;
}

// ---------------------------------------------------------------------------
extern "C" void kernel_launch(void* const* d_in, const int* in_sizes, int n_in,
                              void* d_out, int out_size, void* d_ws, size_t ws_size,
                              hipStream_t stream) {
  const float* x    = (const float*)d_in[0];
  const float* xhat = (const float*)d_in[1];
  const int*   codes= (const int*)d_in[2];
  const float* cb   = (const float*)d_in[3];
  const float* Win  = (const float*)d_in[4];
  const float* bin  = (const float*)d_in[5];
  const float* Wcat = (const float*)d_in[6];
  const float* bcat = (const float*)d_in[7];
  const float* W1   = (const float*)d_in[8];
  const float* b1   = (const float*)d_in[9];
  const float* W2   = (const float*)d_in[10];
  const float* b2   = (const float*)d_in[11];
  const float* Wout = (const float*)d_in[12];
  const float* bout = (const float*)d_in[13];
  float* out = (float*)d_out;

  float* u     = (float*)d_ws;                  // 65536 f (h0 eliminated)
  float* v     = u + K_ * H_;                   // 262144 f
  float* dists = v + B_ * F_ * H_;              // 262144 f
  float* resc  = dists + B_ * F_ * K_;          // 1024 f
  int*   topi  = (int*)(resc + 1024);           // 1024 i
  int*   pad   = topi + 1024;                   // 128 pad (keeps 16B align)
  _Float16* w1f  = (_Float16*)(pad + 128);      // 2*H*HFF halves
  _Float16* w2f  = w1f + 2 * H_ * HFF_;
  _Float16* wof  = w2f + 2 * HFF_ * H_;

  k_prep<<<K_ + B_ * F_ + 2304, 256, 0, stream>>>(cb, Win, bin, Wcat, bcat, xhat,
                                                  W1, W2, Wout, u, v, w1f, w2f, wof);

  k_main<<<B_ * F_ * (K_ / RT), 512, 0, stream>>>(u, v, w1f, b1, w2f, b2,
                                                  wof, bout, cb, xhat, x, dists);
  k_top8<<<B_, 256, 0, stream>>>(dists, topi);
  k_rescore<<<B_ * 8, 256, 0, stream>>>(u, v, W1, b1, W2, b2, Wout, bout, cb, xhat,
                                        x, topi, resc);
  k_final<<<B_, 256, 0, stream>>>(u, v, W1, b1, W2, b2, Wout, bout, cb, xhat,
                                  codes, topi, resc, out);
}

// Round 3
// 587.129 us; speedup vs baseline: 1.5648x; 1.5648x over previous
//
#include <hip/hip_runtime.h>
#include <hip/hip_bf16.h>

// Shapes (fixed): B=128, F=8, K=256, D=256, H=256, HFF=512, L=2, M_PREV=2
#define B_   128
#define F_   8
#define K_   256
#define D_   256
#define H_   256
#define HFF_ 512
#define RT   64   // candidates per block

typedef _Float16 half8  __attribute__((ext_vector_type(8)));  // f16x8 MFMA frag
typedef _Float16 half4v __attribute__((ext_vector_type(4)));
typedef float floatx4   __attribute__((ext_vector_type(4)));  // MFMA acc

#define MFMAH(a,b,c) __builtin_amdgcn_mfma_f32_16x16x32_f16(a,b,c,0,0,0)

// LDS strides (halves): 260 -> 130 dwords == 2 mod 32 (conflict-free b128).
// R12 (= R11 resubmit; R11 bench was an infra failure, no data):
// HFF chunking 4->2 (chunk=256): halves hA re-reads in gemm1, mt=4
// per wave (load:MFMA 0.75->0.5), barriers/layer 8->4.
// LDS: hA 33280 + hmA 33280 + x/xh 2048 + dist 1024 = 69632 B
//      -> 2 blocks/CU x 4 waves = 8 waves/CU.
#define HA_S  260

// ---------------------------------------------------------------------------
// R9: fused prep — one launch for (h0->u), v, and the fp16 weight shuffle.
// blocks [0,256): u[k] = (cb[k]@Win + bin)@Wcat_top   (h0 never hits HBM)
// blocks [256,1280): v[bf] = bcat + xhat[bf]@Wcat_bot
// blocks [1280,3584): weight fragment shuffle (W1/W2/Wout -> fp16 frag order)
__global__ void k_prep(const float* __restrict__ cb, const float* __restrict__ Win,
                       const float* __restrict__ bin, const float* __restrict__ Wcat,
                       const float* __restrict__ bcat, const float* __restrict__ xhat,
                       const float* __restrict__ W1, const float* __restrict__ W2,
                       const float* __restrict__ Wout,
                       float* __restrict__ u, float* __restrict__ v,
                       _Float16* __restrict__ w1f, _Float16* __restrict__ w2f,
                       _Float16* __restrict__ wof) {
  const int blk = blockIdx.x, t = threadIdx.x;
  if (blk < K_) {
    __shared__ float row[D_];
    __shared__ float h0row[H_];
    row[t] = cb[blk * D_ + t];
    __syncthreads();
    float acc = bin[t];
    #pragma unroll 4
    for (int i = 0; i < D_; ++i) acc = fmaf(row[i], Win[i * H_ + t], acc);
    h0row[t] = acc;
    __syncthreads();
    float acc2 = 0.f;
    #pragma unroll 4
    for (int i = 0; i < H_; ++i) acc2 = fmaf(h0row[i], Wcat[i * H_ + t], acc2);
    u[blk * H_ + t] = acc2;
  } else if (blk < K_ + B_ * F_) {
    __shared__ float row2[D_];
    const int bf = blk - K_;
    row2[t] = xhat[bf * D_ + t];
    __syncthreads();
    float acc = bcat[t];
    #pragma unroll 4
    for (int i = 0; i < D_; ++i) acc = fmaf(row2[i], Wcat[(H_ + i) * H_ + t], acc);
    v[bf * H_ + t] = acc;
  } else {
    const int e = (blk - (K_ + B_ * F_)) * 256 + t;
    const float* src; _Float16* dst; int N, NT, le;
    if (e < 262144) {
      const int layer = e >> 17; le = e & 131071;
      src = W1 + layer * (H_ * HFF_); dst = w1f + layer * (H_ * HFF_);
      N = HFF_; NT = 32;
    } else if (e < 524288) {
      const int e2 = e - 262144;
      const int layer = e2 >> 17; le = e2 & 131071;
      src = W2 + layer * (HFF_ * H_); dst = w2f + layer * (HFF_ * H_);
      N = H_; NT = 16;
    } else {
      le = e - 524288; src = Wout; dst = wof; N = D_; NT = 16;
    }
    const int jj = le & 7, lane = (le >> 3) & 63, r = le >> 9;
    const int ntile = r % NT, kstep = r / NT;
    const int row = kstep * 32 + (lane >> 4) * 8 + jj;
    const int colc = ntile * 16 + (lane & 15);
    dst[le] = (_Float16)src[row * N + colc];
  }
}

// ---------------------------------------------------------------------------
// R12 MFMA main kernel: 4 waves, chunk=256 (2 chunks), mt=4 everywhere.
__global__ __launch_bounds__(256, 2) void k_main(
    const float* __restrict__ u, const float* __restrict__ v,
    const _Float16* __restrict__ w1f, const float* __restrict__ b1,
    const _Float16* __restrict__ w2f, const float* __restrict__ b2,
    const _Float16* __restrict__ woutf, const float* __restrict__ bout,
    const float* __restrict__ cb, const float* __restrict__ xhat,
    const float* __restrict__ x, float* __restrict__ dists) {
  __shared__ _Float16 hA[64][HA_S];    // 33280 B
  __shared__ _Float16 hmA[64][HA_S];   // 33280 B (256-wide chunk)
  __shared__ float x_s[D_], xh_s[D_];  // 2048 B
  __shared__ float dist_s[4][64];      // 1024 B

  const int t = threadIdx.x;
  const int blk = blockIdx.x;
  const int bf = blk >> 2, k0 = (blk & 3) << 6;
  const int b = bf >> 3, f = bf & 7;
  const int wave = t >> 6, lane = t & 63;
  const int col = lane & 15, quad = lane >> 4;
  const int lane8 = lane * 8;

  x_s[t]  = x[b * D_ + t];
  xh_s[t] = xhat[bf * D_ + t];

  // stage h = u + v -> fp16, packed 16B writes
  {
    const int r = t >> 2, c0 = (t & 3) * 64;
    const float* up = u + (k0 + r) * H_ + c0;
    const float* vp = v + bf * H_ + c0;
    #pragma unroll
    for (int j = 0; j < 64; j += 8) {
      float4 uA = *(const float4*)(up + j);
      float4 vA = *(const float4*)(vp + j);
      float4 uB = *(const float4*)(up + j + 4);
      float4 vB = *(const float4*)(vp + j + 4);
      half8 hv8;
      hv8[0] = (_Float16)(uA.x + vA.x); hv8[1] = (_Float16)(uA.y + vA.y);
      hv8[2] = (_Float16)(uA.z + vA.z); hv8[3] = (_Float16)(uA.w + vA.w);
      hv8[4] = (_Float16)(uB.x + vB.x); hv8[5] = (_Float16)(uB.y + vB.y);
      hv8[6] = (_Float16)(uB.z + vB.z); hv8[7] = (_Float16)(uB.w + vB.w);
      *(half8*)&hA[r][c0 + j] = hv8;
    }
  }
  __syncthreads();

  const floatx4 zero4 = {0.f, 0.f, 0.f, 0.f};

  #pragma unroll 1
  for (int l = 0; l < 2; ++l) {
    const _Float16* w1_l = w1f + l * (H_ * HFF_);
    const _Float16* w2_l = w2f + l * (HFF_ * H_);
    const float* b1l = b1 + l * HFF_;
    const float* b2l = b2 + l * H_;

    floatx4 acc2[4][4];   // [out-feature tile][candidate-row tile]
    #pragma unroll
    for (int mt = 0; mt < 4; ++mt)
      #pragma unroll
      for (int nt = 0; nt < 4; ++nt) acc2[mt][nt] = zero4;

    #pragma unroll 1
    for (int ch = 0; ch < 2; ++ch) {
      // ---- GEMM1': hm' = relu(W1[:,chunk]^T @ h^T + b1), chunk = 256 ----
      floatx4 acc1[4][4];
      #pragma unroll
      for (int mt = 0; mt < 4; ++mt)
        #pragma unroll
        for (int nt = 0; nt < 4; ++nt) acc1[mt][nt] = zero4;

      // W1 frag order: ntile = ch*16 + wave*4 + mt, kstep = ks
      const _Float16* w1_b = w1_l + (ch * 16 + wave * 4) * 512 + lane8;

      #pragma unroll 2
      for (int ks = 0; ks < 8; ++ks) {
        half8 b0  = *(const half8*)&hA[col][ks * 32 + quad * 8];
        half8 b1v = *(const half8*)&hA[16 + col][ks * 32 + quad * 8];
        half8 b2v = *(const half8*)&hA[32 + col][ks * 32 + quad * 8];
        half8 b3v = *(const half8*)&hA[48 + col][ks * 32 + quad * 8];
        const int ko = ks * 32 * 512;
        #pragma unroll
        for (int mt = 0; mt < 4; ++mt) {
          half8 aw = *(const half8*)(w1_b + ko + mt * 512);
          acc1[mt][0] = MFMAH(aw, b0,  acc1[mt][0]);
          acc1[mt][1] = MFMAH(aw, b1v, acc1[mt][1]);
          acc1[mt][2] = MFMAH(aw, b2v, acc1[mt][2]);
          acc1[mt][3] = MFMAH(aw, b3v, acc1[mt][3]);
        }
      }
      // bias + relu -> fp16, packed 8B stores (4 consecutive features/lane)
      #pragma unroll
      for (int mt = 0; mt < 4; ++mt) {
        const int floc = (wave * 4 + mt) * 16 + quad * 4;
        float4 bb = *(const float4*)&b1l[ch * 256 + floc];
        #pragma unroll
        for (int nt = 0; nt < 4; ++nt) {
          const int row = nt * 16 + col;
          half4v nh;
          #pragma unroll
          for (int p = 0; p < 4; ++p)
            nh[p] = (_Float16)fmaxf(acc1[mt][nt][p] + ((const float*)&bb)[p], 0.f);
          *(half4v*)&hmA[row][floc] = nh;
        }
      }
      __syncthreads();

      // ---- GEMM2': acc2 += W2[chunk,:]^T @ hm'^T, k-range = 256 ----
      // W2 frag order: ntile = wave*4 + mt, kstep = ch*8 + ks
      const _Float16* w2_b = w2_l + (ch * 128 + wave * 4) * 512 + lane8;
      #pragma unroll 2
      for (int ks = 0; ks < 8; ++ks) {
        half8 b0  = *(const half8*)&hmA[col][ks * 32 + quad * 8];
        half8 b1v = *(const half8*)&hmA[16 + col][ks * 32 + quad * 8];
        half8 b2v = *(const half8*)&hmA[32 + col][ks * 32 + quad * 8];
        half8 b3v = *(const half8*)&hmA[48 + col][ks * 32 + quad * 8];
        const int ko = ks * 16 * 512;
        #pragma unroll
        for (int mt = 0; mt < 4; ++mt) {
          half8 aw = *(const half8*)(w2_b + ko + mt * 512);
          acc2[mt][0] = MFMAH(aw, b0,  acc2[mt][0]);
          acc2[mt][1] = MFMAH(aw, b1v, acc2[mt][1]);
          acc2[mt][2] = MFMAH(aw, b2v, acc2[mt][2]);
          acc2[mt][3] = MFMAH(aw, b3v, acc2[mt][3]);
        }
      }
      __syncthreads();
    }

    // ---- residual: h += acc2 + b2, packed 8B read/modify/write ----
    #pragma unroll
    for (int mt = 0; mt < 4; ++mt) {
      const int feat0 = (wave * 4 + mt) * 16 + quad * 4;
      float4 bb = *(const float4*)&b2l[feat0];
      #pragma unroll
      for (int nt = 0; nt < 4; ++nt) {
        const int row = nt * 16 + col;
        half4v oh = *(half4v*)&hA[row][feat0];
        half4v nh;
        #pragma unroll
        for (int p = 0; p < 4; ++p)
          nh[p] = (_Float16)((float)oh[p] + acc2[mt][nt][p] + ((const float*)&bb)[p]);
        *(half4v*)&hA[row][feat0] = nh;
      }
    }
    __syncthreads();
  }

  // ---- GEMM3': cw' = Wout^T @ h^T (+bout+cb+xhat), then distance ----
  floatx4 acc3[4][4];
  #pragma unroll
  for (int mt = 0; mt < 4; ++mt)
    #pragma unroll
    for (int nt = 0; nt < 4; ++nt) acc3[mt][nt] = zero4;

  const _Float16* wo_b = woutf + (wave * 4) * 512 + lane8;
  #pragma unroll 2
  for (int ks = 0; ks < 8; ++ks) {
    half8 b0  = *(const half8*)&hA[col][ks * 32 + quad * 8];
    half8 b1v = *(const half8*)&hA[16 + col][ks * 32 + quad * 8];
    half8 b2v = *(const half8*)&hA[32 + col][ks * 32 + quad * 8];
    half8 b3v = *(const half8*)&hA[48 + col][ks * 32 + quad * 8];
    const int ko = ks * 16 * 512;
    #pragma unroll
    for (int mt = 0; mt < 4; ++mt) {
      half8 aw = *(const half8*)(wo_b + ko + mt * 512);
      acc3[mt][0] = MFMAH(aw, b0,  acc3[mt][0]);
      acc3[mt][1] = MFMAH(aw, b1v, acc3[mt][1]);
      acc3[mt][2] = MFMAH(aw, b2v, acc3[mt][2]);
      acc3[mt][3] = MFMAH(aw, b3v, acc3[mt][3]);
    }
  }

  float s[4] = {0.f, 0.f, 0.f, 0.f};
  #pragma unroll
  for (int mt = 0; mt < 4; ++mt) {
    const int d0 = (wave * 4 + mt) * 16 + quad * 4;
    float4 bo  = *(const float4*)&bout[d0];
    float4 xv  = *(const float4*)&x_s[d0];
    float4 xh4 = *(const float4*)&xh_s[d0];
    #pragma unroll
    for (int nt = 0; nt < 4; ++nt) {
      float4 cbv = *(const float4*)&cb[(k0 + nt * 16 + col) * D_ + d0];
      #pragma unroll
      for (int p = 0; p < 4; ++p) {
        float base = ((const float*)&bo)[p] + ((const float*)&xh4)[p];
        float xx = ((const float*)&xv)[p];
        float cw = acc3[mt][nt][p] + base + ((const float*)&cbv)[p];
        s[nt] += cw * (cw - 2.f * xx);   // -||x||^2 const: argmin-invariant
      }
    }
  }
  #pragma unroll
  for (int nt = 0; nt < 4; ++nt) {
    s[nt] += __shfl_xor(s[nt], 16, 64);
    s[nt] += __shfl_xor(s[nt], 32, 64);
  }
  if (quad == 0) {
    #pragma unroll
    for (int nt = 0; nt < 4; ++nt)
      dist_s[wave][nt * 16 + col] = s[nt];
  }
  __syncthreads();
  if (t < 64) {
    float d = dist_s[0][t] + dist_s[1][t] + dist_s[2][t] + dist_s[3][t];
    dists[b * (F_ * K_) + f * K_ + k0 + t] = d;
  }
}

// ---------------------------------------------------------------------------
// Top-8 candidates per b from approx dists (iterative selection).
__global__ void k_top8(const float* __restrict__ dists, int* __restrict__ topi) {
  __shared__ float ds[F_ * K_];
  __shared__ float bv[256];
  __shared__ int bi_s[256];
  const int b = blockIdx.x, t = threadIdx.x;
  for (int j = t; j < F_ * K_; j += 256) ds[j] = dists[b * (F_ * K_) + j];
  __syncthreads();
  for (int pass = 0; pass < 8; ++pass) {
    float best = 3.4e38f; int bi = 0;
    for (int j = t; j < F_ * K_; j += 256) {
      const float dv = ds[j];
      if (dv < best) { best = dv; bi = j; }
    }
    bv[t] = best; bi_s[t] = bi;
    __syncthreads();
    for (int s = 128; s > 0; s >>= 1) {
      if (t < s) {
        const float ov = bv[t + s]; const int oi = bi_s[t + s];
        if (ov < bv[t] || (ov == bv[t] && oi < bi_s[t])) { bv[t] = ov; bi_s[t] = oi; }
      }
      __syncthreads();
    }
    if (t == 0) { topi[b * 8 + pass] = bi_s[0]; ds[bi_s[0]] = 3.4e38f; }
    __syncthreads();
  }
}

// ---------------------------------------------------------------------------
// Exact fp32 rescore of one candidate row per block (same math as R2 pass).
__global__ void k_rescore(const float* __restrict__ u, const float* __restrict__ v,
                          const float* __restrict__ W1, const float* __restrict__ b1,
                          const float* __restrict__ W2, const float* __restrict__ b2,
                          const float* __restrict__ Wout, const float* __restrict__ bout,
                          const float* __restrict__ cb, const float* __restrict__ xhat,
                          const float* __restrict__ x, const int* __restrict__ topi,
                          float* __restrict__ resc) {
  __shared__ float hs[H_];
  __shared__ float hms[HFF_];
  __shared__ float red[256];
  const int bc = blockIdx.x, t = threadIdx.x;
  const int b = bc >> 3;
  const int idx = topi[bc];
  const int f = idx >> 8, k = idx & 255;
  const int bf = b * F_ + f;

  hs[t] = u[k * H_ + t] + v[bf * H_ + t];
  __syncthreads();
  for (int l = 0; l < 2; ++l) {
    const float* W1l = W1 + l * (H_ * HFF_);
    const float* W2l = W2 + l * (HFF_ * H_);
    float a0 = b1[l * HFF_ + t], a1 = b1[l * HFF_ + 256 + t];
    for (int i = 0; i < H_; ++i) {
      const float hv = hs[i];
      a0 = fmaf(hv, W1l[i * HFF_ + t], a0);
      a1 = fmaf(hv, W1l[i * HFF_ + 256 + t], a1);
    }
    hms[t] = fmaxf(a0, 0.f);
    hms[t + 256] = fmaxf(a1, 0.f);
    __syncthreads();
    float hn = hs[t] + b2[l * H_ + t];
    for (int jj = 0; jj < HFF_; ++jj)
      hn = fmaf(hms[jj], W2l[jj * H_ + t], hn);
    __syncthreads();
    hs[t] = hn;
    __syncthreads();
  }
  float cw = bout[t] + cb[k * D_ + t] + xhat[bf * D_ + t];
  for (int i = 0; i < H_; ++i) cw = fmaf(hs[i], Wout[i * D_ + t], cw);
  red[t] = cw * (cw - 2.f * x[b * D_ + t]);
  __syncthreads();
  for (int s = 128; s > 0; s >>= 1) {
    if (t < s) red[t] += red[t + s];
    __syncthreads();
  }
  if (t == 0) resc[bc] = red[0];
}

// ---------------------------------------------------------------------------
// Pick exact argmin among 8 rescored candidates; recompute winner; write out.
__global__ void k_final(const float* __restrict__ u, const float* __restrict__ v,
                        const float* __restrict__ W1, const float* __restrict__ b1,
                        const float* __restrict__ W2, const float* __restrict__ b2,
                        const float* __restrict__ Wout, const float* __restrict__ bout,
                        const float* __restrict__ cb, const float* __restrict__ xhat,
                        const int* __restrict__ codes, const int* __restrict__ topi,
                        const float* __restrict__ resc, float* __restrict__ out) {
  __shared__ float hs[H_];
  __shared__ float hms[HFF_];
  __shared__ int idx_sh;
  const int b = blockIdx.x, t = threadIdx.x;
  if (t == 0) {
    float bd = 3.4e38f; int bidx = 1 << 30;
    for (int c = 0; c < 8; ++c) {
      const float d = resc[b * 8 + c];
      const int ix = topi[b * 8 + c];
      if (d < bd || (d == bd && ix < bidx)) { bd = d; bidx = ix; }
    }
    idx_sh = bidx;
  }
  __syncthreads();
  const int idx = idx_sh;
  const int f = idx >> 8, k = idx & 255;
  const int bf = b * F_ + f;

  hs[t] = u[k * H_ + t] + v[bf * H_ + t];
  __syncthreads();
  for (int l = 0; l < 2; ++l) {
    const float* W1l = W1 + l * (H_ * HFF_);
    const float* W2l = W2 + l * (HFF_ * H_);
    float a0 = b1[l * HFF_ + t], a1 = b1[l * HFF_ + 256 + t];
    for (int i = 0; i < H_; ++i) {
      const float hv = hs[i];
      a0 = fmaf(hv, W1l[i * HFF_ + t], a0);
      a1 = fmaf(hv, W1l[i * HFF_ + 256 + t], a1);
    }
    hms[t] = fmaxf(a0, 0.f);
    hms[t + 256] = fmaxf(a1, 0.f);
    __syncthreads();
    float hn = hs[t] + b2[l * H_ + t];
    for (int jj = 0; jj < HFF_; ++jj)
      hn = fmaf(hms[jj], W2l[jj * H_ + t], hn);
    __syncthreads();
    hs[t] = hn;
    __syncthreads();
  }
  float cw = bout[t] + cb[k * D_ + t] + xhat[bf * D_ + t];
  for (int i = 0; i < H_; ++i) cw = fmaf(hs[i], Wout[i * D_ + t], cw);

  out[b * D_ + t] = cw;
  if (t < 2)
    out[B_ * D_ + t * B_ + b] = (float)codes[t * B_ + b];
  else if (t == 2)
    out[B_ * D_ + 2 * B_ + b] = (float)idx;
}

// ---------------------------------------------------------------------------
extern "C" void kernel_launch(void* const* d_in, const int* in_sizes, int n_in,
                              void* d_out, int out_size, void* d_ws, size_t ws_size,
                              hipStream_t stream) {
  const float* x    = (const float*)d_in[0];
  const float* xhat = (const float*)d_in[1];
  const int*   codes= (const int*)d_in[2];
  const float* cb   = (const float*)d_in[3];
  const float* Win  = (const float*)d_in[4];
  const float* bin  = (const float*)d_in[5];
  const float* Wcat = (const float*)d_in[6];
  const float* bcat = (const float*)d_in[7];
  const float* W1   = (const float*)d_in[8];
  const float* b1   = (const float*)d_in[9];
  const float* W2   = (const float*)d_in[10];
  const float* b2   = (const float*)d_in[11];
  const float* Wout = (const float*)d_in[12];
  const float* bout = (const float*)d_in[13];
  float* out = (float*)d_out;

  float* u     = (float*)d_ws;                  // 65536 f (h0 eliminated)
  float* v     = u + K_ * H_;                   // 262144 f
  float* dists = v + B_ * F_ * H_;              // 262144 f
  float* resc  = dists + B_ * F_ * K_;          // 1024 f
  int*   topi  = (int*)(resc + 1024);           // 1024 i
  int*   pad   = topi + 1024;                   // 128 pad (keeps 16B align)
  _Float16* w1f  = (_Float16*)(pad + 128);      // 2*H*HFF halves
  _Float16* w2f  = w1f + 2 * H_ * HFF_;
  _Float16* wof  = w2f + 2 * HFF_ * H_;

  k_prep<<<K_ + B_ * F_ + 2304, 256, 0, stream>>>(cb, Win, bin, Wcat, bcat, xhat,
                                                  W1, W2, Wout, u, v, w1f, w2f, wof);

  k_main<<<B_ * F_ * (K_ / RT), 256, 0, stream>>>(u, v, w1f, b1, w2f, b2,
                                                  wof, bout, cb, xhat, x, dists);
  k_top8<<<B_, 256, 0, stream>>>(dists, topi);
  k_rescore<<<B_ * 8, 256, 0, stream>>>(u, v, W1, b1, W2, b2, Wout, bout, cb, xhat,
                                        x, topi, resc);
  k_final<<<B_, 256, 0, stream>>>(u, v, W1, b1, W2, b2, Wout, bout, cb, xhat,
                                  codes, topi, resc, out);
}